// Round 1
// baseline (2748.059 us; speedup 1.0000x reference)
//
#include <hip/hip_runtime.h>

#define L_ 4096
#define D_ 1536
#define NH 12
#define HD 128

typedef __attribute__((ext_vector_type(8))) __bf16 bf16x8;
typedef __attribute__((ext_vector_type(8))) unsigned short ushort8v;
typedef __attribute__((ext_vector_type(4))) float floatx4;

__device__ __forceinline__ unsigned short f2bf(float f) {
  union { float f; unsigned int u; } v; v.f = f;
  unsigned int u = v.u;
  return (unsigned short)((u + 0x7fffu + ((u >> 16) & 1u)) >> 16);
}
__device__ __forceinline__ float bf2f(unsigned short h) {
  union { unsigned int u; float f; } v; v.u = ((unsigned int)h) << 16;
  return v.f;
}

// ---------------- fp32 -> bf16 conversion (8 elems/thread) ----------------
__global__ __launch_bounds__(256) void cvt_f32_bf16(const float* __restrict__ in,
                                                    unsigned short* __restrict__ out,
                                                    int n8) {
  int i = blockIdx.x * 256 + threadIdx.x;
  if (i >= n8) return;
  const float4* p = (const float4*)(in + (size_t)i * 8);
  float4 a = p[0], b = p[1];
  ushort8v o;
  o[0] = f2bf(a.x); o[1] = f2bf(a.y); o[2] = f2bf(a.z); o[3] = f2bf(a.w);
  o[4] = f2bf(b.x); o[5] = f2bf(b.y); o[6] = f2bf(b.z); o[7] = f2bf(b.w);
  *(ushort8v*)(out + (size_t)i * 8) = o;
}

// ---------------- bf16 MFMA GEMM: C[m,n] = sum_k A[m,k]*B[n,k] + bias[n] ----
// m97-style: 128x128 tile, K-tile 32, global_load_lds width 16, 4 waves,
// each wave 64x64 via 4x4 grid of 16x16x32 MFMA.
template <bool OBF>
__global__ __launch_bounds__(256) void gemm_bt(const unsigned short* __restrict__ A,
                                               const unsigned short* __restrict__ Bw,
                                               const float* __restrict__ bias,
                                               void* __restrict__ Cout,
                                               int M, int Nn, int K) {
  __shared__ unsigned short As[128 * 32];
  __shared__ unsigned short Bs[128 * 32];
  int t = threadIdx.x;
  int lane = t & 63, wv = t >> 6;
  int m0 = blockIdx.y * 128, n0 = blockIdx.x * 128;
  int wm = (wv & 1) * 64, wn = (wv >> 1) * 64;
  floatx4 zero = {0.f, 0.f, 0.f, 0.f};
  floatx4 acc[4][4];
#pragma unroll
  for (int i = 0; i < 4; ++i)
#pragma unroll
    for (int j = 0; j < 4; ++j) acc[i][j] = zero;
  int fm = lane & 15, fk = (lane >> 4) * 8;

  for (int kt = 0; kt < K; kt += 32) {
    __syncthreads();
#pragma unroll
    for (int it = 0; it < 2; ++it) {
      int c = it * 256 + t;           // 16B chunk index; 4 chunks per row of 32 bf16
      int row = c >> 2, col = (c & 3) * 8;
      const unsigned short* ga = A + (size_t)(m0 + row) * K + kt + col;
      const unsigned short* gb = Bw + (size_t)(n0 + row) * K + kt + col;
      __builtin_amdgcn_global_load_lds(
          (const __attribute__((address_space(1))) void*)ga,
          (__attribute__((address_space(3))) void*)((char*)As + (it * 256 + wv * 64) * 16),
          16, 0, 0);
      __builtin_amdgcn_global_load_lds(
          (const __attribute__((address_space(1))) void*)gb,
          (__attribute__((address_space(3))) void*)((char*)Bs + (it * 256 + wv * 64) * 16),
          16, 0, 0);
    }
    __syncthreads();
    bf16x8 af[4], bfr[4];
#pragma unroll
    for (int i = 0; i < 4; ++i) {
      af[i]  = *(const bf16x8*)&As[(wm + 16 * i + fm) * 32 + fk];
      bfr[i] = *(const bf16x8*)&Bs[(wn + 16 * i + fm) * 32 + fk];
    }
#pragma unroll
    for (int i = 0; i < 4; ++i)
#pragma unroll
      for (int j = 0; j < 4; ++j)
        acc[i][j] = __builtin_amdgcn_mfma_f32_16x16x32_bf16(af[i], bfr[j], acc[i][j], 0, 0, 0);
  }

  int fr = (lane >> 4) * 4;
#pragma unroll
  for (int j = 0; j < 4; ++j) {
    int col = n0 + wn + 16 * j + fm;
    float bz = bias[col];
#pragma unroll
    for (int i = 0; i < 4; ++i) {
#pragma unroll
      for (int r = 0; r < 4; ++r) {
        int row = m0 + wm + 16 * i + fr + r;
        float val = acc[i][j][r] + bz;
        if (OBF) ((unsigned short*)Cout)[(size_t)row * Nn + col] = f2bf(val);
        else     ((float*)Cout)[(size_t)row * Nn + col] = val;
      }
    }
  }
}

// ---------------- fused RMSNorm (over D) + 3-axis RoPE, in-place bf16 -------
__global__ __launch_bounds__(256) void rmsrope(unsigned short* __restrict__ qb,
                                               unsigned short* __restrict__ kb,
                                               const float* __restrict__ gq,
                                               const float* __restrict__ gk,
                                               const float* __restrict__ fcos,
                                               const float* __restrict__ fsin,
                                               const int* __restrict__ grid_sizes) {
  int row = blockIdx.x;
  unsigned short* buf = (blockIdx.y == 0) ? qb : kb;
  const float* g = (blockIdx.y == 0) ? gq : gk;
  int t = threadIdx.x;
  float xr[3], xi[3];
#pragma unroll
  for (int i = 0; i < 3; ++i) {
    int p = t + i * 256;   // pair index 0..767
    unsigned int raw = *(const unsigned int*)&buf[(size_t)row * D_ + 2 * p];
    xr[i] = bf2f((unsigned short)(raw & 0xffffu));
    xi[i] = bf2f((unsigned short)(raw >> 16));
  }
  float ss = 0.f;
#pragma unroll
  for (int i = 0; i < 3; ++i) ss += xr[i] * xr[i] + xi[i] * xi[i];
  for (int off = 32; off > 0; off >>= 1) ss += __shfl_down(ss, off);
  __shared__ float red[4];
  if ((t & 63) == 0) red[t >> 6] = ss;
  __syncthreads();
  float rs = rsqrtf((red[0] + red[1] + red[2] + red[3]) * (1.0f / D_) + 1e-6f);

  int gf = grid_sizes[0], gh = grid_sizes[1], gw = grid_sizes[2];
  int sl = gf * gh * gw;
  int hw = gh * gw;
  int fi = row / hw, rem = row - fi * hw;
  int hi = rem / gw, wi = rem - hi * gw;
  bool dorope = row < sl;
#pragma unroll
  for (int i = 0; i < 3; ++i) {
    int p = t + i * 256;
    int j = p & 63;                     // complex index within head (c=64)
    float a = xr[i] * rs * g[2 * p];
    float b = xi[i] * rs * g[2 * p + 1];
    if (dorope) {
      int pos = (j < 22) ? fi : ((j < 43) ? hi : wi);  // c1=22, c1+c2=43
      float cs = fcos[pos * 64 + j], sn = fsin[pos * 64 + j];
      float oa = a * cs - b * sn;
      float ob = a * sn + b * cs;
      a = oa; b = ob;
    }
    unsigned int packed = (unsigned int)f2bf(a) | ((unsigned int)f2bf(b) << 16);
    *(unsigned int*)&buf[(size_t)row * D_ + 2 * p] = packed;
  }
}

// ---------------- flash attention, fp32 compute, bf16 in/out ----------------
#define TQ 64
#define TK 32
#define QST 136   // bf16 stride (pad 8) -> bank offset 8/row pair-step: 2-way max
#define KST 132   // fp32 stride (pad 4) -> bank offset 4/row: conflict-free patterns

__global__ __launch_bounds__(256) void attn(const unsigned short* __restrict__ Qb,
                                            const unsigned short* __restrict__ Kb,
                                            const unsigned short* __restrict__ Vb,
                                            unsigned short* __restrict__ Ob,
                                            const int* __restrict__ seq_lens) {
  __shared__ unsigned short Qs[TQ * QST];  // 17408 B
  __shared__ float Ks[TK * KST];           // 16896 B
  __shared__ float Vs[TK * KST];           // 16896 B
  __shared__ float S[TQ * 33];             // 8448 B
  __shared__ float mI[TQ], lI[TQ], alf[TQ];

  int t = threadIdx.x;
  int h = blockIdx.y;
  int q0 = blockIdx.x * TQ;
  int seqlen = seq_lens[0];
  int rg = t >> 3, lk = t & 7;
  int r0 = rg * 2, r1 = r0 + 1;

  // stage Q tile (bf16 passthrough)
#pragma unroll
  for (int i = 0; i < 4; ++i) {
    int f = t + i * 256;
    int row = f >> 4, c = f & 15;
    ushort8v v = *(const ushort8v*)&Qb[((size_t)(q0 + row) * NH + h) * HD + c * 8];
    *(ushort8v*)&Qs[row * QST + c * 8] = v;
  }
  if (t < TQ) { mI[t] = -3.0e38f; lI[t] = 0.f; alf[t] = 0.f; }

  float acc0[16], acc1[16];
#pragma unroll
  for (int e = 0; e < 16; ++e) { acc0[e] = 0.f; acc1[e] = 0.f; }
  const float scl = 0.08838834764831845f;  // 1/sqrt(128)

  for (int kt = 0; kt < L_; kt += TK) {
    __syncthreads();
    // stage K/V tile, convert to fp32
#pragma unroll
    for (int i = 0; i < 2; ++i) {
      int f = t + i * 256;
      int row = f >> 4, c = f & 15;
      size_t gaddr = ((size_t)(kt + row) * NH + h) * HD + c * 8;
      ushort8v kv = *(const ushort8v*)&Kb[gaddr];
      ushort8v vv = *(const ushort8v*)&Vb[gaddr];
      *(float4*)&Ks[row * KST + c * 8]     = make_float4(bf2f(kv[0]), bf2f(kv[1]), bf2f(kv[2]), bf2f(kv[3]));
      *(float4*)&Ks[row * KST + c * 8 + 4] = make_float4(bf2f(kv[4]), bf2f(kv[5]), bf2f(kv[6]), bf2f(kv[7]));
      *(float4*)&Vs[row * KST + c * 8]     = make_float4(bf2f(vv[0]), bf2f(vv[1]), bf2f(vv[2]), bf2f(vv[3]));
      *(float4*)&Vs[row * KST + c * 8 + 4] = make_float4(bf2f(vv[4]), bf2f(vv[5]), bf2f(vv[6]), bf2f(vv[7]));
    }
    __syncthreads();

    // S phase: rows r0,r1 x keys (lk + 8j)
    float s0[4] = {0.f, 0.f, 0.f, 0.f}, s1[4] = {0.f, 0.f, 0.f, 0.f};
#pragma unroll 4
    for (int d8 = 0; d8 < 16; ++d8) {
      ushort8v q0v = *(const ushort8v*)&Qs[r0 * QST + d8 * 8];
      ushort8v q1v = *(const ushort8v*)&Qs[r1 * QST + d8 * 8];
      float qa[8], qc[8];
#pragma unroll
      for (int e = 0; e < 8; ++e) { qa[e] = bf2f(q0v[e]); qc[e] = bf2f(q1v[e]); }
#pragma unroll
      for (int j = 0; j < 4; ++j) {
        const float* kp = &Ks[(lk + 8 * j) * KST + d8 * 8];
        float4 k0 = *(const float4*)kp;
        float4 k1 = *(const float4*)(kp + 4);
        s0[j] += qa[0] * k0.x + qa[1] * k0.y + qa[2] * k0.z + qa[3] * k0.w
               + qa[4] * k1.x + qa[5] * k1.y + qa[6] * k1.z + qa[7] * k1.w;
        s1[j] += qc[0] * k0.x + qc[1] * k0.y + qc[2] * k0.z + qc[3] * k0.w
               + qc[4] * k1.x + qc[5] * k1.y + qc[6] * k1.z + qc[7] * k1.w;
      }
    }
#pragma unroll
    for (int j = 0; j < 4; ++j) { s0[j] *= scl; s1[j] *= scl; }

    // online softmax (8-lane groups per row)
    float mx0 = fmaxf(fmaxf(s0[0], s0[1]), fmaxf(s0[2], s0[3]));
    float mx1 = fmaxf(fmaxf(s1[0], s1[1]), fmaxf(s1[2], s1[3]));
#pragma unroll
    for (int off = 1; off < 8; off <<= 1) {
      mx0 = fmaxf(mx0, __shfl_xor(mx0, off));
      mx1 = fmaxf(mx1, __shfl_xor(mx1, off));
    }
    float mo0 = mI[r0], mo1 = mI[r1];
    float mn0 = fmaxf(mo0, mx0), mn1 = fmaxf(mo1, mx1);
    float sum0 = 0.f, sum1 = 0.f;
#pragma unroll
    for (int j = 0; j < 4; ++j) {
      int key = kt + lk + 8 * j;
      float p0 = (key < seqlen) ? __expf(s0[j] - mn0) : 0.f;
      float p1 = (key < seqlen) ? __expf(s1[j] - mn1) : 0.f;
      sum0 += p0; sum1 += p1;
      S[r0 * 33 + lk + 8 * j] = p0;
      S[r1 * 33 + lk + 8 * j] = p1;
    }
#pragma unroll
    for (int off = 1; off < 8; off <<= 1) {
      sum0 += __shfl_xor(sum0, off);
      sum1 += __shfl_xor(sum1, off);
    }
    if (lk == 0) {
      float a0 = __expf(mo0 - mn0);
      float a1 = __expf(mo1 - mn1);
      alf[r0] = a0; mI[r0] = mn0; lI[r0] = lI[r0] * a0 + sum0;
      alf[r1] = a1; mI[r1] = mn1; lI[r1] = lI[r1] * a1 + sum1;
    }
    __syncthreads();

    // PV phase
    float a0 = alf[r0], a1 = alf[r1];
#pragma unroll
    for (int e = 0; e < 16; ++e) { acc0[e] *= a0; acc1[e] *= a1; }
#pragma unroll 8
    for (int j = 0; j < TK; ++j) {
      float p0 = S[r0 * 33 + j], p1 = S[r1 * 33 + j];
#pragma unroll
      for (int i4 = 0; i4 < 4; ++i4) {
        float4 vv = *(const float4*)&Vs[j * KST + (lk + 8 * i4) * 4];
        acc0[i4 * 4 + 0] += p0 * vv.x; acc0[i4 * 4 + 1] += p0 * vv.y;
        acc0[i4 * 4 + 2] += p0 * vv.z; acc0[i4 * 4 + 3] += p0 * vv.w;
        acc1[i4 * 4 + 0] += p1 * vv.x; acc1[i4 * 4 + 1] += p1 * vv.y;
        acc1[i4 * 4 + 2] += p1 * vv.z; acc1[i4 * 4 + 3] += p1 * vv.w;
      }
    }
  }

  float inv0 = 1.0f / lI[r0], inv1 = 1.0f / lI[r1];
#pragma unroll
  for (int i4 = 0; i4 < 4; ++i4) {
    int cb = (lk + 8 * i4) * 4;
    size_t b0 = ((size_t)(q0 + r0) * NH + h) * HD + cb;
    size_t b1 = ((size_t)(q0 + r1) * NH + h) * HD + cb;
    ushort4 o0 = make_ushort4(f2bf(acc0[i4 * 4 + 0] * inv0), f2bf(acc0[i4 * 4 + 1] * inv0),
                              f2bf(acc0[i4 * 4 + 2] * inv0), f2bf(acc0[i4 * 4 + 3] * inv0));
    ushort4 o1 = make_ushort4(f2bf(acc1[i4 * 4 + 0] * inv1), f2bf(acc1[i4 * 4 + 1] * inv1),
                              f2bf(acc1[i4 * 4 + 2] * inv1), f2bf(acc1[i4 * 4 + 3] * inv1));
    *(ushort4*)&Ob[b0] = o0;
    *(ushort4*)&Ob[b1] = o1;
  }
}

// ---------------- launch ----------------
extern "C" void kernel_launch(void* const* d_in, const int* in_sizes, int n_in,
                              void* d_out, int out_size, void* d_ws, size_t ws_size,
                              hipStream_t stream) {
  (void)in_sizes; (void)n_in; (void)out_size; (void)ws_size;
  const float* x    = (const float*)d_in[0];
  const int* seqln  = (const int*)d_in[1];
  const int* gsz    = (const int*)d_in[2];
  const float* fcos = (const float*)d_in[3];
  const float* fsin = (const float*)d_in[4];
  const float* Wq = (const float*)d_in[5];
  const float* bq = (const float*)d_in[6];
  const float* Wk = (const float*)d_in[7];
  const float* bk = (const float*)d_in[8];
  const float* Wv = (const float*)d_in[9];
  const float* bv = (const float*)d_in[10];
  const float* Wo = (const float*)d_in[11];
  const float* bo = (const float*)d_in[12];
  const float* gq = (const float*)d_in[13];
  const float* gk = (const float*)d_in[14];

  char* ws = (char*)d_ws;
  size_t LD2 = (size_t)L_ * D_ * 2;      // 12.58 MB
  size_t WD2 = (size_t)D_ * D_ * 2;      // 4.72 MB
  unsigned short* xb = (unsigned short*)(ws);            // also reused as attn out
  unsigned short* qb = (unsigned short*)(ws + LD2);
  unsigned short* kb = (unsigned short*)(ws + 2 * LD2);
  unsigned short* vb = (unsigned short*)(ws + 3 * LD2);
  unsigned short* wb = (unsigned short*)(ws + 4 * LD2);  // single reusable weight buf
  unsigned short* ab = xb;                                // alias: x no longer needed

  int nx8 = L_ * D_ / 8, nw8 = D_ * D_ / 8;
  dim3 gg(D_ / 128, L_ / 128);

  cvt_f32_bf16<<<(nx8 + 255) / 256, 256, 0, stream>>>(x, xb, nx8);

  cvt_f32_bf16<<<(nw8 + 255) / 256, 256, 0, stream>>>(Wq, wb, nw8);
  gemm_bt<true><<<gg, 256, 0, stream>>>(xb, wb, bq, qb, L_, D_, D_);
  cvt_f32_bf16<<<(nw8 + 255) / 256, 256, 0, stream>>>(Wk, wb, nw8);
  gemm_bt<true><<<gg, 256, 0, stream>>>(xb, wb, bk, kb, L_, D_, D_);
  cvt_f32_bf16<<<(nw8 + 255) / 256, 256, 0, stream>>>(Wv, wb, nw8);
  gemm_bt<true><<<gg, 256, 0, stream>>>(xb, wb, bv, vb, L_, D_, D_);

  rmsrope<<<dim3(L_, 2), 256, 0, stream>>>(qb, kb, gq, gk, fcos, fsin, gsz);

  attn<<<dim3(L_ / TQ, NH), 256, 0, stream>>>(qb, kb, vb, ab, seqln);

  cvt_f32_bf16<<<(nw8 + 255) / 256, 256, 0, stream>>>(Wo, wb, nw8);
  gemm_bt<false><<<gg, 256, 0, stream>>>(ab, wb, bo, d_out, L_, D_, D_);
}

// Round 2
// 599.356 us; speedup vs baseline: 4.5850x; 4.5850x over previous
//
#include <hip/hip_runtime.h>

#define L_ 4096
#define D_ 1536
#define NH 12
#define HD 128

typedef __attribute__((ext_vector_type(8))) __bf16 bf16x8;
typedef __attribute__((ext_vector_type(8))) unsigned short ushort8v;
typedef __attribute__((ext_vector_type(4))) float floatx4;

__device__ __forceinline__ unsigned short f2bf(float f) {
  union { float f; unsigned int u; } v; v.f = f;
  unsigned int u = v.u;
  return (unsigned short)((u + 0x7fffu + ((u >> 16) & 1u)) >> 16);
}
__device__ __forceinline__ float bf2f(unsigned short h) {
  union { unsigned int u; float f; } v; v.u = ((unsigned int)h) << 16;
  return v.f;
}

// ---------------- fp32 -> bf16 conversion (8 elems/thread) ----------------
__global__ __launch_bounds__(256) void cvt_f32_bf16(const float* __restrict__ in,
                                                    unsigned short* __restrict__ out,
                                                    int n8) {
  int i = blockIdx.x * 256 + threadIdx.x;
  if (i >= n8) return;
  const float4* p = (const float4*)(in + (size_t)i * 8);
  float4 a = p[0], b = p[1];
  ushort8v o;
  o[0] = f2bf(a.x); o[1] = f2bf(a.y); o[2] = f2bf(a.z); o[3] = f2bf(a.w);
  o[4] = f2bf(b.x); o[5] = f2bf(b.y); o[6] = f2bf(b.z); o[7] = f2bf(b.w);
  *(ushort8v*)(out + (size_t)i * 8) = o;
}

// ---------------- bf16 MFMA GEMM: C[m,n] = sum_k A[m,k]*B[n,k] + bias[n] ----
// MODE 0: fp32 output row-major. MODE 1: bf16 row-major. MODE 2: bf16 output
// TRANSPOSED (C^T, [Nn][M]) with packed ushort4 stores (4 consecutive rows).
template <int MODE>
__global__ __launch_bounds__(256) void gemm_bt(const unsigned short* __restrict__ A,
                                               const unsigned short* __restrict__ Bw,
                                               const float* __restrict__ bias,
                                               void* __restrict__ Cout,
                                               int M, int Nn, int K) {
  __shared__ unsigned short As[128 * 32];
  __shared__ unsigned short Bs[128 * 32];
  int t = threadIdx.x;
  int lane = t & 63, wv = t >> 6;
  int m0 = blockIdx.y * 128, n0 = blockIdx.x * 128;
  int wm = (wv & 1) * 64, wn = (wv >> 1) * 64;
  floatx4 zero = {0.f, 0.f, 0.f, 0.f};
  floatx4 acc[4][4];
#pragma unroll
  for (int i = 0; i < 4; ++i)
#pragma unroll
    for (int j = 0; j < 4; ++j) acc[i][j] = zero;
  int fm = lane & 15, fk = (lane >> 4) * 8;

  for (int kt = 0; kt < K; kt += 32) {
    __syncthreads();
#pragma unroll
    for (int it = 0; it < 2; ++it) {
      int c = it * 256 + t;
      int row = c >> 2, col = (c & 3) * 8;
      const unsigned short* ga = A + (size_t)(m0 + row) * K + kt + col;
      const unsigned short* gb = Bw + (size_t)(n0 + row) * K + kt + col;
      __builtin_amdgcn_global_load_lds(
          (const __attribute__((address_space(1))) void*)ga,
          (__attribute__((address_space(3))) void*)((char*)As + (it * 256 + wv * 64) * 16),
          16, 0, 0);
      __builtin_amdgcn_global_load_lds(
          (const __attribute__((address_space(1))) void*)gb,
          (__attribute__((address_space(3))) void*)((char*)Bs + (it * 256 + wv * 64) * 16),
          16, 0, 0);
    }
    __syncthreads();
    bf16x8 af[4], bfr[4];
#pragma unroll
    for (int i = 0; i < 4; ++i) {
      af[i]  = *(const bf16x8*)&As[(wm + 16 * i + fm) * 32 + fk];
      bfr[i] = *(const bf16x8*)&Bs[(wn + 16 * i + fm) * 32 + fk];
    }
#pragma unroll
    for (int i = 0; i < 4; ++i)
#pragma unroll
      for (int j = 0; j < 4; ++j)
        acc[i][j] = __builtin_amdgcn_mfma_f32_16x16x32_bf16(af[i], bfr[j], acc[i][j], 0, 0, 0);
  }

  int fr = (lane >> 4) * 4;
#pragma unroll
  for (int j = 0; j < 4; ++j) {
    int col = n0 + wn + 16 * j + fm;
    float bz = bias[col];
#pragma unroll
    for (int i = 0; i < 4; ++i) {
      int row0 = m0 + wm + 16 * i + fr;
      if (MODE == 2) {
        ushort4 pk = make_ushort4(f2bf(acc[i][j][0] + bz), f2bf(acc[i][j][1] + bz),
                                  f2bf(acc[i][j][2] + bz), f2bf(acc[i][j][3] + bz));
        *(ushort4*)&((unsigned short*)Cout)[(size_t)col * M + row0] = pk;
      } else {
#pragma unroll
        for (int r = 0; r < 4; ++r) {
          float val = acc[i][j][r] + bz;
          if (MODE == 1) ((unsigned short*)Cout)[(size_t)(row0 + r) * Nn + col] = f2bf(val);
          else           ((float*)Cout)[(size_t)(row0 + r) * Nn + col] = val;
        }
      }
    }
  }
}

// ---------------- fused RMSNorm (over D) + 3-axis RoPE, in-place bf16 -------
__global__ __launch_bounds__(256) void rmsrope(unsigned short* __restrict__ qb,
                                               unsigned short* __restrict__ kb,
                                               const float* __restrict__ gq,
                                               const float* __restrict__ gk,
                                               const float* __restrict__ fcos,
                                               const float* __restrict__ fsin,
                                               const int* __restrict__ grid_sizes) {
  int row = blockIdx.x;
  unsigned short* buf = (blockIdx.y == 0) ? qb : kb;
  const float* g = (blockIdx.y == 0) ? gq : gk;
  int t = threadIdx.x;
  float xr[3], xi[3];
#pragma unroll
  for (int i = 0; i < 3; ++i) {
    int p = t + i * 256;
    unsigned int raw = *(const unsigned int*)&buf[(size_t)row * D_ + 2 * p];
    xr[i] = bf2f((unsigned short)(raw & 0xffffu));
    xi[i] = bf2f((unsigned short)(raw >> 16));
  }
  float ss = 0.f;
#pragma unroll
  for (int i = 0; i < 3; ++i) ss += xr[i] * xr[i] + xi[i] * xi[i];
  for (int off = 32; off > 0; off >>= 1) ss += __shfl_down(ss, off);
  __shared__ float red[4];
  if ((t & 63) == 0) red[t >> 6] = ss;
  __syncthreads();
  float rs = rsqrtf((red[0] + red[1] + red[2] + red[3]) * (1.0f / D_) + 1e-6f);

  int gf = grid_sizes[0], gh = grid_sizes[1], gw = grid_sizes[2];
  int sl = gf * gh * gw;
  int hw = gh * gw;
  int fi = row / hw, rem = row - fi * hw;
  int hi = rem / gw, wi = rem - hi * gw;
  bool dorope = row < sl;
#pragma unroll
  for (int i = 0; i < 3; ++i) {
    int p = t + i * 256;
    int j = p & 63;
    float a = xr[i] * rs * g[2 * p];
    float b = xi[i] * rs * g[2 * p + 1];
    if (dorope) {
      int pos = (j < 22) ? fi : ((j < 43) ? hi : wi);
      float cs = fcos[pos * 64 + j], sn = fsin[pos * 64 + j];
      float oa = a * cs - b * sn;
      float ob = a * sn + b * cs;
      a = oa; b = ob;
    }
    unsigned int packed = (unsigned int)f2bf(a) | ((unsigned int)f2bf(b) << 16);
    *(unsigned int*)&buf[(size_t)row * D_ + 2 * p] = packed;
  }
}

// ---------------- MFMA flash attention (S^T trick) ----------------
// Per block: head h, 128 q rows. 4 waves x 32 q. TK=32 keys per step.
// S^T = K·Q^T via mfma_16x16x32 (A=K rows -> C rows=key, B=Q rows -> C cols=q).
// Key permutation pi(mi, 4g+r) = 8g+4mi+r applied at K-staging so the P
// C-fragment bits are exactly the A-fragment of the PV mfma (k-slot 4mi+r).
// V pre-transposed globally (Vtg[D][L]) by the V-GEMM epilogue.
#define KST 136  // Ks LDS stride (bf16), 272 B: 16B-aligned rows, 2-way banks
#define VST 40   // Vt LDS stride (bf16), 80 B: 16B-aligned rows

__global__ __launch_bounds__(256) void attn2(const unsigned short* __restrict__ Qb,
                                             const unsigned short* __restrict__ Kb,
                                             const unsigned short* __restrict__ Vtg,
                                             unsigned short* __restrict__ Ob,
                                             const int* __restrict__ seq_lens) {
  __shared__ unsigned short Ks[32 * KST];   // 8704 B
  __shared__ unsigned short Vt[128 * VST];  // 10240 B
  int t = threadIdx.x, lane = t & 63, wv = t >> 6;
  int h = blockIdx.y, q0 = blockIdx.x * 128;
  int seqlen = seq_lens[0];
  int wq0 = wv * 32;
  int fl = lane & 15, fg = lane >> 4;

  // Q B-fragments: loop-invariant, registers only. B[n=q][k=d].
  bf16x8 qf[2][4];
#pragma unroll
  for (int nj = 0; nj < 2; ++nj)
#pragma unroll
    for (int kd = 0; kd < 4; ++kd)
      qf[nj][kd] = *(const bf16x8*)&Qb[((size_t)(q0 + wq0 + nj * 16 + fl) * NH + h) * HD + kd * 32 + fg * 8];

  floatx4 o[2][8];
  floatx4 zero = {0.f, 0.f, 0.f, 0.f};
#pragma unroll
  for (int nj = 0; nj < 2; ++nj)
#pragma unroll
    for (int n = 0; n < 8; ++n) o[nj][n] = zero;
  float mr[2] = {-3.0e38f, -3.0e38f}, lr[2] = {0.f, 0.f};
  const float scl = 0.08838834764831845f;  // 1/sqrt(128)

  for (int kt = 0; kt < L_; kt += 32) {
    __syncthreads();
#pragma unroll
    for (int i = 0; i < 2; ++i) {
      int f = t + i * 256;
      int krow = f >> 4, c = f & 15;
      int ldsrow = ((krow & 4) << 2) + ((krow >> 3) << 2) + (krow & 3);  // key permutation
      *(bf16x8*)&Ks[ldsrow * KST + c * 8] =
          *(const bf16x8*)&Kb[((size_t)(kt + krow) * NH + h) * HD + c * 8];
      int vrow = f >> 2, c2 = f & 3;
      *(bf16x8*)&Vt[vrow * VST + c2 * 8] =
          *(const bf16x8*)&Vtg[(size_t)(h * HD + vrow) * L_ + kt + c2 * 8];
    }
    __syncthreads();

    // S^T: rows = permuted keys (2 tiles of 16), cols = q (2 tiles of 16)
    floatx4 s[2][2];
    s[0][0] = zero; s[0][1] = zero; s[1][0] = zero; s[1][1] = zero;
#pragma unroll
    for (int kd = 0; kd < 4; ++kd)
#pragma unroll
      for (int mi = 0; mi < 2; ++mi) {
        bf16x8 kf = *(const bf16x8*)&Ks[(mi * 16 + fl) * KST + kd * 32 + fg * 8];
        s[mi][0] = __builtin_amdgcn_mfma_f32_16x16x32_bf16(kf, qf[0][kd], s[mi][0], 0, 0, 0);
        s[mi][1] = __builtin_amdgcn_mfma_f32_16x16x32_bf16(kf, qf[1][kd], s[mi][1], 0, 0, 0);
      }

    // online softmax: this lane owns q = nj*16 + fl (replicated over 4 fg groups)
    bf16x8 pb[2];
    float alf[2];
#pragma unroll
    for (int nj = 0; nj < 2; ++nj) {
      float sv[8];
#pragma unroll
      for (int mi = 0; mi < 2; ++mi)
#pragma unroll
        for (int r = 0; r < 4; ++r) {
          float v = s[mi][nj][r] * scl;
          int key = kt + fg * 8 + mi * 4 + r;  // permuted key identity
          sv[mi * 4 + r] = (key < seqlen) ? v : -1.0e30f;
        }
      float mx = sv[0];
#pragma unroll
      for (int j = 1; j < 8; ++j) mx = fmaxf(mx, sv[j]);
      mx = fmaxf(mx, __shfl_xor(mx, 16));
      mx = fmaxf(mx, __shfl_xor(mx, 32));
      float mo = mr[nj], mn = fmaxf(mo, mx);
      float al = __expf(mo - mn);
      float p[8], sum = 0.f;
#pragma unroll
      for (int j = 0; j < 8; ++j) { p[j] = __expf(sv[j] - mn); sum += p[j]; }
      sum += __shfl_xor(sum, 16);
      sum += __shfl_xor(sum, 32);
      lr[nj] = lr[nj] * al + sum;
      mr[nj] = mn;
      alf[nj] = al;
      union { unsigned short u[8]; bf16x8 v; } pk;
#pragma unroll
      for (int j = 0; j < 8; ++j) pk.u[j] = f2bf(p[j]);  // slot j=4mi+r -> key fg*8+j
      pb[nj] = pk.v;
    }

    // rescale O by alpha (O rows = q via (fg*4+r); alpha holder lane = q&15)
#pragma unroll
    for (int nj = 0; nj < 2; ++nj) {
      float a0 = __shfl(alf[nj], fg * 4 + 0);
      float a1 = __shfl(alf[nj], fg * 4 + 1);
      float a2 = __shfl(alf[nj], fg * 4 + 2);
      float a3 = __shfl(alf[nj], fg * 4 + 3);
#pragma unroll
      for (int n = 0; n < 8; ++n) {
        o[nj][n][0] *= a0; o[nj][n][1] *= a1; o[nj][n][2] *= a2; o[nj][n][3] *= a3;
      }
    }

    // PV: A = pb (in-register), B = Vt rows (d), k = key (natural order)
#pragma unroll
    for (int n = 0; n < 8; ++n) {
      bf16x8 vf = *(const bf16x8*)&Vt[(n * 16 + fl) * VST + fg * 8];
      o[0][n] = __builtin_amdgcn_mfma_f32_16x16x32_bf16(pb[0], vf, o[0][n], 0, 0, 0);
      o[1][n] = __builtin_amdgcn_mfma_f32_16x16x32_bf16(pb[1], vf, o[1][n], 0, 0, 0);
    }
  }

  // epilogue: divide by l, write O (row = q0+wq0+nj*16+fg*4+r, col = n*16+fl)
#pragma unroll
  for (int nj = 0; nj < 2; ++nj) {
    float inv = 1.0f / lr[nj];
    float i0 = __shfl(inv, fg * 4 + 0);
    float i1 = __shfl(inv, fg * 4 + 1);
    float i2 = __shfl(inv, fg * 4 + 2);
    float i3 = __shfl(inv, fg * 4 + 3);
    int rowb = q0 + wq0 + nj * 16 + fg * 4;
#pragma unroll
    for (int n = 0; n < 8; ++n) {
      int dcol = n * 16 + fl;
      Ob[((size_t)(rowb + 0) * NH + h) * HD + dcol] = f2bf(o[nj][n][0] * i0);
      Ob[((size_t)(rowb + 1) * NH + h) * HD + dcol] = f2bf(o[nj][n][1] * i1);
      Ob[((size_t)(rowb + 2) * NH + h) * HD + dcol] = f2bf(o[nj][n][2] * i2);
      Ob[((size_t)(rowb + 3) * NH + h) * HD + dcol] = f2bf(o[nj][n][3] * i3);
    }
  }
}

// ---------------- launch ----------------
extern "C" void kernel_launch(void* const* d_in, const int* in_sizes, int n_in,
                              void* d_out, int out_size, void* d_ws, size_t ws_size,
                              hipStream_t stream) {
  (void)in_sizes; (void)n_in; (void)out_size; (void)ws_size;
  const float* x    = (const float*)d_in[0];
  const int* seqln  = (const int*)d_in[1];
  const int* gsz    = (const int*)d_in[2];
  const float* fcos = (const float*)d_in[3];
  const float* fsin = (const float*)d_in[4];
  const float* Wq = (const float*)d_in[5];
  const float* bq = (const float*)d_in[6];
  const float* Wk = (const float*)d_in[7];
  const float* bk = (const float*)d_in[8];
  const float* Wv = (const float*)d_in[9];
  const float* bv = (const float*)d_in[10];
  const float* Wo = (const float*)d_in[11];
  const float* bo = (const float*)d_in[12];
  const float* gq = (const float*)d_in[13];
  const float* gk = (const float*)d_in[14];

  char* ws = (char*)d_ws;
  size_t LD2 = (size_t)L_ * D_ * 2;
  unsigned short* xb  = (unsigned short*)(ws);            // x bf16; later attn out
  unsigned short* qb  = (unsigned short*)(ws + LD2);
  unsigned short* kb  = (unsigned short*)(ws + 2 * LD2);
  unsigned short* vtb = (unsigned short*)(ws + 3 * LD2);  // V TRANSPOSED [D][L]
  unsigned short* wb  = (unsigned short*)(ws + 4 * LD2);  // reusable weight buf
  unsigned short* ab  = xb;

  int nx8 = L_ * D_ / 8, nw8 = D_ * D_ / 8;
  dim3 gg(D_ / 128, L_ / 128);

  cvt_f32_bf16<<<(nx8 + 255) / 256, 256, 0, stream>>>(x, xb, nx8);

  cvt_f32_bf16<<<(nw8 + 255) / 256, 256, 0, stream>>>(Wq, wb, nw8);
  gemm_bt<1><<<gg, 256, 0, stream>>>(xb, wb, bq, qb, L_, D_, D_);
  cvt_f32_bf16<<<(nw8 + 255) / 256, 256, 0, stream>>>(Wk, wb, nw8);
  gemm_bt<1><<<gg, 256, 0, stream>>>(xb, wb, bk, kb, L_, D_, D_);
  cvt_f32_bf16<<<(nw8 + 255) / 256, 256, 0, stream>>>(Wv, wb, nw8);
  gemm_bt<2><<<gg, 256, 0, stream>>>(xb, wb, bv, vtb, L_, D_, D_);

  rmsrope<<<dim3(L_, 2), 256, 0, stream>>>(qb, kb, gq, gk, fcos, fsin, gsz);

  attn2<<<dim3(L_ / 128, NH), 256, 0, stream>>>(qb, kb, vtb, ab, seqln);

  cvt_f32_bf16<<<(nw8 + 255) / 256, 256, 0, stream>>>(Wo, wb, nw8);
  gemm_bt<0><<<gg, 256, 0, stream>>>(ab, wb, bo, d_out, L_, D_, D_);
}

// Round 3
// 579.800 us; speedup vs baseline: 4.7397x; 1.0337x over previous
//
#include <hip/hip_runtime.h>

#define L_ 4096
#define D_ 1536
#define NH 12
#define HD 128

typedef __attribute__((ext_vector_type(8))) __bf16 bf16x8;
typedef __attribute__((ext_vector_type(8))) unsigned short ushort8v;
typedef __attribute__((ext_vector_type(4))) float floatx4;

#if __has_builtin(__builtin_amdgcn_exp2f)
#define EXP2F(x) __builtin_amdgcn_exp2f(x)
#else
#define EXP2F(x) exp2f(x)
#endif

__device__ __forceinline__ unsigned short f2bf(float f) {
  union { float f; unsigned int u; } v; v.f = f;
  unsigned int u = v.u;
  return (unsigned short)((u + 0x7fffu + ((u >> 16) & 1u)) >> 16);
}
__device__ __forceinline__ float bf2f(unsigned short h) {
  union { unsigned int u; float f; } v; v.u = ((unsigned int)h) << 16;
  return v.f;
}

// ---------------- fp32 -> bf16 conversion (8 elems/thread) ----------------
__global__ __launch_bounds__(256) void cvt_f32_bf16(const float* __restrict__ in,
                                                    unsigned short* __restrict__ out,
                                                    int n8) {
  int i = blockIdx.x * 256 + threadIdx.x;
  if (i >= n8) return;
  const float4* p = (const float4*)(in + (size_t)i * 8);
  float4 a = p[0], b = p[1];
  ushort8v o;
  o[0] = f2bf(a.x); o[1] = f2bf(a.y); o[2] = f2bf(a.z); o[3] = f2bf(a.w);
  o[4] = f2bf(b.x); o[5] = f2bf(b.y); o[6] = f2bf(b.z); o[7] = f2bf(b.w);
  *(ushort8v*)(out + (size_t)i * 8) = o;
}

// ---------------- bf16 MFMA GEMM: C[m,n] = sum_k A[m,k]*B[n,k] + bias[n] ----
// MODE 0: fp32 row-major. MODE 1: bf16 row-major. MODE 2: bf16 output in
// K-TILED-TRANSPOSED layout [M/32][Nn][32] (for attention V fragments),
// packed ushort4 stores (4 consecutive m-rows contiguous in last dim).
template <int MODE>
__global__ __launch_bounds__(256) void gemm_bt(const unsigned short* __restrict__ A,
                                               const unsigned short* __restrict__ Bw,
                                               const float* __restrict__ bias,
                                               void* __restrict__ Cout,
                                               int M, int Nn, int K) {
  __shared__ unsigned short As[128 * 32];
  __shared__ unsigned short Bs[128 * 32];
  int t = threadIdx.x;
  int lane = t & 63, wv = t >> 6;
  int m0 = blockIdx.y * 128, n0 = blockIdx.x * 128;
  int wm = (wv & 1) * 64, wn = (wv >> 1) * 64;
  floatx4 zero = {0.f, 0.f, 0.f, 0.f};
  floatx4 acc[4][4];
#pragma unroll
  for (int i = 0; i < 4; ++i)
#pragma unroll
    for (int j = 0; j < 4; ++j) acc[i][j] = zero;
  int fm = lane & 15, fk = (lane >> 4) * 8;

  for (int kt = 0; kt < K; kt += 32) {
    __syncthreads();
#pragma unroll
    for (int it = 0; it < 2; ++it) {
      int c = it * 256 + t;
      int row = c >> 2, col = (c & 3) * 8;
      const unsigned short* ga = A + (size_t)(m0 + row) * K + kt + col;
      const unsigned short* gb = Bw + (size_t)(n0 + row) * K + kt + col;
      __builtin_amdgcn_global_load_lds(
          (const __attribute__((address_space(1))) void*)ga,
          (__attribute__((address_space(3))) void*)((char*)As + (it * 256 + wv * 64) * 16),
          16, 0, 0);
      __builtin_amdgcn_global_load_lds(
          (const __attribute__((address_space(1))) void*)gb,
          (__attribute__((address_space(3))) void*)((char*)Bs + (it * 256 + wv * 64) * 16),
          16, 0, 0);
    }
    __syncthreads();
    bf16x8 af[4], bfr[4];
#pragma unroll
    for (int i = 0; i < 4; ++i) {
      af[i]  = *(const bf16x8*)&As[(wm + 16 * i + fm) * 32 + fk];
      bfr[i] = *(const bf16x8*)&Bs[(wn + 16 * i + fm) * 32 + fk];
    }
#pragma unroll
    for (int i = 0; i < 4; ++i)
#pragma unroll
      for (int j = 0; j < 4; ++j)
        acc[i][j] = __builtin_amdgcn_mfma_f32_16x16x32_bf16(af[i], bfr[j], acc[i][j], 0, 0, 0);
  }

  int fr = (lane >> 4) * 4;
#pragma unroll
  for (int j = 0; j < 4; ++j) {
    int col = n0 + wn + 16 * j + fm;
    float bz = bias[col];
#pragma unroll
    for (int i = 0; i < 4; ++i) {
      int row0 = m0 + wm + 16 * i + fr;
      if (MODE == 2) {
        ushort4 pk = make_ushort4(f2bf(acc[i][j][0] + bz), f2bf(acc[i][j][1] + bz),
                                  f2bf(acc[i][j][2] + bz), f2bf(acc[i][j][3] + bz));
        size_t off = (size_t)(row0 >> 5) * Nn * 32 + (size_t)col * 32 + (row0 & 31);
        *(ushort4*)&((unsigned short*)Cout)[off] = pk;
      } else {
#pragma unroll
        for (int r = 0; r < 4; ++r) {
          float val = acc[i][j][r] + bz;
          if (MODE == 1) ((unsigned short*)Cout)[(size_t)(row0 + r) * Nn + col] = f2bf(val);
          else           ((float*)Cout)[(size_t)(row0 + r) * Nn + col] = val;
        }
      }
    }
  }
}

// ---------------- fused RMSNorm (over D) + 3-axis RoPE, in-place bf16 -------
// For the Q buffer (blockIdx.y==0), output is additionally scaled by
// (1/sqrt(HD))*log2(e) so attention can use raw exp2 with no per-elem scale.
__global__ __launch_bounds__(256) void rmsrope(unsigned short* __restrict__ qb,
                                               unsigned short* __restrict__ kb,
                                               const float* __restrict__ gq,
                                               const float* __restrict__ gk,
                                               const float* __restrict__ fcos,
                                               const float* __restrict__ fsin,
                                               const int* __restrict__ grid_sizes) {
  int row = blockIdx.x;
  unsigned short* buf = (blockIdx.y == 0) ? qb : kb;
  const float* g = (blockIdx.y == 0) ? gq : gk;
  float osc = (blockIdx.y == 0) ? 0.1275174475f : 1.0f;  // log2(e)/sqrt(128)
  int t = threadIdx.x;
  float xr[3], xi[3];
#pragma unroll
  for (int i = 0; i < 3; ++i) {
    int p = t + i * 256;
    unsigned int raw = *(const unsigned int*)&buf[(size_t)row * D_ + 2 * p];
    xr[i] = bf2f((unsigned short)(raw & 0xffffu));
    xi[i] = bf2f((unsigned short)(raw >> 16));
  }
  float ss = 0.f;
#pragma unroll
  for (int i = 0; i < 3; ++i) ss += xr[i] * xr[i] + xi[i] * xi[i];
  for (int off = 32; off > 0; off >>= 1) ss += __shfl_down(ss, off);
  __shared__ float red[4];
  if ((t & 63) == 0) red[t >> 6] = ss;
  __syncthreads();
  float rs = rsqrtf((red[0] + red[1] + red[2] + red[3]) * (1.0f / D_) + 1e-6f);

  int gf = grid_sizes[0], gh = grid_sizes[1], gw = grid_sizes[2];
  int sl = gf * gh * gw;
  int hw = gh * gw;
  int fi = row / hw, rem = row - fi * hw;
  int hi = rem / gw, wi = rem - hi * gw;
  bool dorope = row < sl;
#pragma unroll
  for (int i = 0; i < 3; ++i) {
    int p = t + i * 256;
    int j = p & 63;
    float a = xr[i] * rs * g[2 * p];
    float b = xi[i] * rs * g[2 * p + 1];
    if (dorope) {
      int pos = (j < 22) ? fi : ((j < 43) ? hi : wi);
      float cs = fcos[pos * 64 + j], sn = fsin[pos * 64 + j];
      float oa = a * cs - b * sn;
      float ob = a * sn + b * cs;
      a = oa; b = ob;
    }
    a *= osc; b *= osc;
    unsigned int packed = (unsigned int)f2bf(a) | ((unsigned int)f2bf(b) << 16);
    *(unsigned int*)&buf[(size_t)row * D_ + 2 * p] = packed;
  }
}

// ---------------- MFMA flash attention v3: 1 wave/block, no LDS, no barriers
// 64 q rows per wave. S^T = K·Q^T (key perm pi folded into direct-global K
// fragment addressing), exp2 softmax with NO running max (scale pre-folded
// into Q; scores bounded so fp32 exp2 cannot overflow), P packed to bf16 in
// registers as the PV A-operand. V read from K-tiled layout [L/32][D][32].
__global__ __launch_bounds__(64, 1) void attn3(const unsigned short* __restrict__ Qb,
                                               const unsigned short* __restrict__ Kb,
                                               const unsigned short* __restrict__ Vt,
                                               unsigned short* __restrict__ Ob,
                                               const int* __restrict__ seq_lens) {
  int lane = threadIdx.x;
  int h = blockIdx.y;
  int q0 = blockIdx.x * 64;
  int seqlen = seq_lens[0];
  int fl = lane & 15, fg = lane >> 4;

  // Q B-fragments (pre-scaled in rmsrope): B[n=q][k=d]
  bf16x8 qf[4][4];
#pragma unroll
  for (int nj = 0; nj < 4; ++nj)
#pragma unroll
    for (int kd = 0; kd < 4; ++kd)
      qf[nj][kd] = *(const bf16x8*)&Qb[((size_t)(q0 + nj * 16 + fl) * NH + h) * HD + kd * 32 + fg * 8];

  // K fragment addresses: A row (mi*16+fl) holds key pi^-1(row)
  int kr0 = ((fl & 12) << 1) | (fl & 3);   // mi=0
  int kr1 = kr0 + 4;                        // mi=1
  const unsigned short* kp0 = Kb + ((size_t)kr0 * NH + h) * HD + fg * 8;
  const unsigned short* kp1 = Kb + ((size_t)kr1 * NH + h) * HD + fg * 8;
  // V fragments from tiled layout: elem off = (kt>>5)*D_*32 + d*32 + kcol
  const unsigned short* vp = Vt + (size_t)(h * HD + fl) * 32 + fg * 8;
  const int KSTEP = 32 * NH * HD;  // elems per 32-key step
  const int VSTEP = D_ * 32;

  floatx4 o[4][8];
  floatx4 zero = {0.f, 0.f, 0.f, 0.f};
#pragma unroll
  for (int nj = 0; nj < 4; ++nj)
#pragma unroll
    for (int nt = 0; nt < 8; ++nt) o[nj][nt] = zero;
  float lr[4] = {0.f, 0.f, 0.f, 0.f};

  auto loadK = [&](bf16x8 (&kf)[2][4], const unsigned short* p0, const unsigned short* p1) {
#pragma unroll
    for (int kd = 0; kd < 4; ++kd) {
      kf[0][kd] = *(const bf16x8*)(p0 + kd * 32);
      kf[1][kd] = *(const bf16x8*)(p1 + kd * 32);
    }
  };
  auto loadV = [&](bf16x8 (&vf)[8], const unsigned short* p) {
#pragma unroll
    for (int nt = 0; nt < 8; ++nt) vf[nt] = *(const bf16x8*)(p + nt * 512);
  };

  auto step = [&](int kt, bf16x8 (&kf)[2][4], bf16x8 (&vf)[8]) {
    floatx4 s[2][4];
#pragma unroll
    for (int mi = 0; mi < 2; ++mi)
#pragma unroll
      for (int nj = 0; nj < 4; ++nj) s[mi][nj] = zero;
#pragma unroll
    for (int kd = 0; kd < 4; ++kd)
#pragma unroll
      for (int mi = 0; mi < 2; ++mi)
#pragma unroll
        for (int nj = 0; nj < 4; ++nj)
          s[mi][nj] = __builtin_amdgcn_mfma_f32_16x16x32_bf16(kf[mi][kd], qf[nj][kd], s[mi][nj], 0, 0, 0);

    bf16x8 pb[4];
    bool full = (kt + 32 <= seqlen);
#pragma unroll
    for (int nj = 0; nj < 4; ++nj) {
      float p[8];
      if (full) {
#pragma unroll
        for (int mi = 0; mi < 2; ++mi)
#pragma unroll
          for (int r = 0; r < 4; ++r) p[mi * 4 + r] = EXP2F(s[mi][nj][r]);
      } else {
#pragma unroll
        for (int mi = 0; mi < 2; ++mi)
#pragma unroll
          for (int r = 0; r < 4; ++r) {
            int key = kt + fg * 8 + mi * 4 + r;
            p[mi * 4 + r] = (key < seqlen) ? EXP2F(s[mi][nj][r]) : 0.f;
          }
      }
      float sum = ((p[0] + p[1]) + (p[2] + p[3])) + ((p[4] + p[5]) + (p[6] + p[7]));
      sum += __shfl_xor(sum, 16);
      sum += __shfl_xor(sum, 32);
      lr[nj] += sum;
      union { unsigned int u[4]; bf16x8 v; } pk;
#pragma unroll
      for (int jj = 0; jj < 4; ++jj) {
        unsigned int a = __builtin_bit_cast(unsigned int, p[2 * jj]) + 0x8000u;
        unsigned int b = __builtin_bit_cast(unsigned int, p[2 * jj + 1]) + 0x8000u;
        pk.u[jj] = (a >> 16) | (b & 0xffff0000u);
      }
      pb[nj] = pk.v;
    }

#pragma unroll
    for (int nt = 0; nt < 8; ++nt) {
      bf16x8 vv = vf[nt];
#pragma unroll
      for (int nj = 0; nj < 4; ++nj)
        o[nj][nt] = __builtin_amdgcn_mfma_f32_16x16x32_bf16(pb[nj], vv, o[nj][nt], 0, 0, 0);
    }
  };

  bf16x8 ka[2][4], kb2[2][4], va[8], vb[8];
  loadK(ka, kp0, kp1);
  loadV(va, vp);

  for (int kt = 0; kt < L_; kt += 64) {
    kp0 += KSTEP; kp1 += KSTEP; vp += VSTEP;
    loadK(kb2, kp0, kp1);
    loadV(vb, vp);
    step(kt, ka, va);
    if (kt + 64 < L_) {
      kp0 += KSTEP; kp1 += KSTEP; vp += VSTEP;
      loadK(ka, kp0, kp1);
      loadV(va, vp);
    }
    step(kt + 32, kb2, vb);
  }

  // epilogue: O /= l ; row q = q0+nj*16+fg*4+r, col d = nt*16+fl
#pragma unroll
  for (int nj = 0; nj < 4; ++nj) {
    float inv = 1.0f / lr[nj];
    float i0 = __shfl(inv, fg * 4 + 0);
    float i1 = __shfl(inv, fg * 4 + 1);
    float i2 = __shfl(inv, fg * 4 + 2);
    float i3 = __shfl(inv, fg * 4 + 3);
    int rowb = q0 + nj * 16 + fg * 4;
#pragma unroll
    for (int nt = 0; nt < 8; ++nt) {
      int dcol = h * HD + nt * 16 + fl;
      Ob[(size_t)(rowb + 0) * D_ + dcol] = f2bf(o[nj][nt][0] * i0);
      Ob[(size_t)(rowb + 1) * D_ + dcol] = f2bf(o[nj][nt][1] * i1);
      Ob[(size_t)(rowb + 2) * D_ + dcol] = f2bf(o[nj][nt][2] * i2);
      Ob[(size_t)(rowb + 3) * D_ + dcol] = f2bf(o[nj][nt][3] * i3);
    }
  }
}

// ---------------- launch ----------------
extern "C" void kernel_launch(void* const* d_in, const int* in_sizes, int n_in,
                              void* d_out, int out_size, void* d_ws, size_t ws_size,
                              hipStream_t stream) {
  (void)in_sizes; (void)n_in; (void)out_size; (void)ws_size;
  const float* x    = (const float*)d_in[0];
  const int* seqln  = (const int*)d_in[1];
  const int* gsz    = (const int*)d_in[2];
  const float* fcos = (const float*)d_in[3];
  const float* fsin = (const float*)d_in[4];
  const float* Wq = (const float*)d_in[5];
  const float* bq = (const float*)d_in[6];
  const float* Wk = (const float*)d_in[7];
  const float* bk = (const float*)d_in[8];
  const float* Wv = (const float*)d_in[9];
  const float* bv = (const float*)d_in[10];
  const float* Wo = (const float*)d_in[11];
  const float* bo = (const float*)d_in[12];
  const float* gq = (const float*)d_in[13];
  const float* gk = (const float*)d_in[14];

  char* ws = (char*)d_ws;
  size_t LD2 = (size_t)L_ * D_ * 2;
  unsigned short* xb  = (unsigned short*)(ws);            // x bf16; later attn out
  unsigned short* qb  = (unsigned short*)(ws + LD2);
  unsigned short* kb  = (unsigned short*)(ws + 2 * LD2);
  unsigned short* vtb = (unsigned short*)(ws + 3 * LD2);  // V, K-tiled transposed
  unsigned short* wb  = (unsigned short*)(ws + 4 * LD2);  // reusable weight buf
  unsigned short* ab  = xb;

  int nx8 = L_ * D_ / 8, nw8 = D_ * D_ / 8;
  dim3 gg(D_ / 128, L_ / 128);

  cvt_f32_bf16<<<(nx8 + 255) / 256, 256, 0, stream>>>(x, xb, nx8);

  cvt_f32_bf16<<<(nw8 + 255) / 256, 256, 0, stream>>>(Wq, wb, nw8);
  gemm_bt<1><<<gg, 256, 0, stream>>>(xb, wb, bq, qb, L_, D_, D_);
  cvt_f32_bf16<<<(nw8 + 255) / 256, 256, 0, stream>>>(Wk, wb, nw8);
  gemm_bt<1><<<gg, 256, 0, stream>>>(xb, wb, bk, kb, L_, D_, D_);
  cvt_f32_bf16<<<(nw8 + 255) / 256, 256, 0, stream>>>(Wv, wb, nw8);
  gemm_bt<2><<<gg, 256, 0, stream>>>(xb, wb, bv, vtb, L_, D_, D_);

  rmsrope<<<dim3(L_, 2), 256, 0, stream>>>(qb, kb, gq, gk, fcos, fsin, gsz);

  attn3<<<dim3(L_ / 64, NH), 64, 0, stream>>>(qb, kb, vtb, ab, seqln);

  cvt_f32_bf16<<<(nw8 + 255) / 256, 256, 0, stream>>>(Wo, wb, nw8);
  gemm_bt<0><<<gg, 256, 0, stream>>>(ab, wb, bo, d_out, L_, D_, D_);
}

// Round 4
// 521.984 us; speedup vs baseline: 5.2646x; 1.1108x over previous
//
#include <hip/hip_runtime.h>

#define L_ 4096
#define D_ 1536
#define NH 12
#define HD 128

typedef __attribute__((ext_vector_type(8))) __bf16 bf16x8;
typedef __attribute__((ext_vector_type(8))) unsigned short ushort8v;
typedef __attribute__((ext_vector_type(4))) float floatx4;

#if __has_builtin(__builtin_amdgcn_exp2f)
#define EXP2F(x) __builtin_amdgcn_exp2f(x)
#else
#define EXP2F(x) exp2f(x)
#endif

__device__ __forceinline__ unsigned short f2bf(float f) {
  union { float f; unsigned int u; } v; v.f = f;
  unsigned int u = v.u;
  return (unsigned short)((u + 0x7fffu + ((u >> 16) & 1u)) >> 16);
}
__device__ __forceinline__ float bf2f(unsigned short h) {
  union { unsigned int u; float f; } v; v.u = ((unsigned int)h) << 16;
  return v.f;
}

// ---------------- fp32 -> bf16 conversion (8 elems/thread) ----------------
__global__ __launch_bounds__(256) void cvt_f32_bf16(const float* __restrict__ in,
                                                    unsigned short* __restrict__ out,
                                                    int n8) {
  int i = blockIdx.x * 256 + threadIdx.x;
  if (i >= n8) return;
  const float4* p = (const float4*)(in + (size_t)i * 8);
  float4 a = p[0], b = p[1];
  ushort8v o;
  o[0] = f2bf(a.x); o[1] = f2bf(a.y); o[2] = f2bf(a.z); o[3] = f2bf(a.w);
  o[4] = f2bf(b.x); o[5] = f2bf(b.y); o[6] = f2bf(b.z); o[7] = f2bf(b.w);
  *(ushort8v*)(out + (size_t)i * 8) = o;
}

// ---------------- GEMM core (m97 structure), shared by both GEMM kernels ----
// C[m,n] = sum_k A[m,k]*B[n,k] + bias[n].
// MODE 0: fp32 row-major. MODE 1: bf16 row-major. MODE 2: bf16 K-tiled
// transposed [M/32][Nn][32] (attention V layout), ushort4 packed stores.
template <int MODE>
__device__ __forceinline__ void gemm_core(const unsigned short* __restrict__ A,
                                          const unsigned short* __restrict__ Bw,
                                          const float* __restrict__ bias,
                                          void* __restrict__ Cout,
                                          int M, int Nn, int K,
                                          int m0, int n0,
                                          unsigned short* As, unsigned short* Bs) {
  int t = threadIdx.x;
  int lane = t & 63, wv = t >> 6;
  int wm = (wv & 1) * 64, wn = (wv >> 1) * 64;
  floatx4 zero = {0.f, 0.f, 0.f, 0.f};
  floatx4 acc[4][4];
#pragma unroll
  for (int i = 0; i < 4; ++i)
#pragma unroll
    for (int j = 0; j < 4; ++j) acc[i][j] = zero;
  int fm = lane & 15, fk = (lane >> 4) * 8;

  for (int kt = 0; kt < K; kt += 32) {
    __syncthreads();
#pragma unroll
    for (int it = 0; it < 2; ++it) {
      int c = it * 256 + t;
      int row = c >> 2, col = (c & 3) * 8;
      const unsigned short* ga = A + (size_t)(m0 + row) * K + kt + col;
      const unsigned short* gb = Bw + (size_t)(n0 + row) * K + kt + col;
      __builtin_amdgcn_global_load_lds(
          (const __attribute__((address_space(1))) void*)ga,
          (__attribute__((address_space(3))) void*)((char*)As + (it * 256 + wv * 64) * 16),
          16, 0, 0);
      __builtin_amdgcn_global_load_lds(
          (const __attribute__((address_space(1))) void*)gb,
          (__attribute__((address_space(3))) void*)((char*)Bs + (it * 256 + wv * 64) * 16),
          16, 0, 0);
    }
    __syncthreads();
    bf16x8 af[4], bfr[4];
#pragma unroll
    for (int i = 0; i < 4; ++i) {
      af[i]  = *(const bf16x8*)&As[(wm + 16 * i + fm) * 32 + fk];
      bfr[i] = *(const bf16x8*)&Bs[(wn + 16 * i + fm) * 32 + fk];
    }
#pragma unroll
    for (int i = 0; i < 4; ++i)
#pragma unroll
      for (int j = 0; j < 4; ++j)
        acc[i][j] = __builtin_amdgcn_mfma_f32_16x16x32_bf16(af[i], bfr[j], acc[i][j], 0, 0, 0);
  }

  int fr = (lane >> 4) * 4;
#pragma unroll
  for (int j = 0; j < 4; ++j) {
    int col = n0 + wn + 16 * j + fm;
    float bz = bias[col];
#pragma unroll
    for (int i = 0; i < 4; ++i) {
      int row0 = m0 + wm + 16 * i + fr;
      if (MODE == 2) {
        ushort4 pk = make_ushort4(f2bf(acc[i][j][0] + bz), f2bf(acc[i][j][1] + bz),
                                  f2bf(acc[i][j][2] + bz), f2bf(acc[i][j][3] + bz));
        size_t off = (size_t)(row0 >> 5) * Nn * 32 + (size_t)col * 32 + (row0 & 31);
        *(ushort4*)&((unsigned short*)Cout)[off] = pk;
      } else {
#pragma unroll
        for (int r = 0; r < 4; ++r) {
          float val = acc[i][j][r] + bz;
          if (MODE == 1) ((unsigned short*)Cout)[(size_t)(row0 + r) * Nn + col] = f2bf(val);
          else           ((float*)Cout)[(size_t)(row0 + r) * Nn + col] = val;
        }
      }
    }
  }
}

template <int MODE>
__global__ __launch_bounds__(256) void gemm_bt(const unsigned short* __restrict__ A,
                                               const unsigned short* __restrict__ Bw,
                                               const float* __restrict__ bias,
                                               void* __restrict__ Cout,
                                               int M, int Nn, int K) {
  __shared__ unsigned short As[128 * 32];
  __shared__ unsigned short Bs[128 * 32];
  gemm_core<MODE>(A, Bw, bias, Cout, M, Nn, K, blockIdx.y * 128, blockIdx.x * 128, As, Bs);
}

// Fused QKV: one dispatch, 1152 blocks. blockIdx.x selects {Q,K,V} x n-tile.
__global__ __launch_bounds__(256) void gemm_qkv(const unsigned short* __restrict__ xb,
                                                const unsigned short* __restrict__ wq,
                                                const unsigned short* __restrict__ wk,
                                                const unsigned short* __restrict__ wv,
                                                const float* __restrict__ bq,
                                                const float* __restrict__ bk,
                                                const float* __restrict__ bv,
                                                unsigned short* __restrict__ outq,
                                                unsigned short* __restrict__ outk,
                                                unsigned short* __restrict__ outv) {
  __shared__ unsigned short As[128 * 32];
  __shared__ unsigned short Bs[128 * 32];
  int which = blockIdx.x / (D_ / 128);
  int n0 = (blockIdx.x % (D_ / 128)) * 128;
  int m0 = blockIdx.y * 128;
  if (which == 0)
    gemm_core<1>(xb, wq, bq, outq, L_, D_, D_, m0, n0, As, Bs);
  else if (which == 1)
    gemm_core<1>(xb, wk, bk, outk, L_, D_, D_, m0, n0, As, Bs);
  else
    gemm_core<2>(xb, wv, bv, outv, L_, D_, D_, m0, n0, As, Bs);
}

// ---------------- fused RMSNorm (over D) + 3-axis RoPE, in-place bf16 -------
// Q buffer additionally scaled by log2(e)/sqrt(HD) for exp2 softmax.
__global__ __launch_bounds__(256) void rmsrope(unsigned short* __restrict__ qb,
                                               unsigned short* __restrict__ kb,
                                               const float* __restrict__ gq,
                                               const float* __restrict__ gk,
                                               const float* __restrict__ fcos,
                                               const float* __restrict__ fsin,
                                               const int* __restrict__ grid_sizes) {
  int row = blockIdx.x;
  unsigned short* buf = (blockIdx.y == 0) ? qb : kb;
  const float* g = (blockIdx.y == 0) ? gq : gk;
  float osc = (blockIdx.y == 0) ? 0.1275174475f : 1.0f;  // log2(e)/sqrt(128)
  int t = threadIdx.x;
  float xr[3], xi[3];
#pragma unroll
  for (int i = 0; i < 3; ++i) {
    int p = t + i * 256;
    unsigned int raw = *(const unsigned int*)&buf[(size_t)row * D_ + 2 * p];
    xr[i] = bf2f((unsigned short)(raw & 0xffffu));
    xi[i] = bf2f((unsigned short)(raw >> 16));
  }
  float ss = 0.f;
#pragma unroll
  for (int i = 0; i < 3; ++i) ss += xr[i] * xr[i] + xi[i] * xi[i];
  for (int off = 32; off > 0; off >>= 1) ss += __shfl_down(ss, off);
  __shared__ float red[4];
  if ((t & 63) == 0) red[t >> 6] = ss;
  __syncthreads();
  float rs = rsqrtf((red[0] + red[1] + red[2] + red[3]) * (1.0f / D_) + 1e-6f);

  int gf = grid_sizes[0], gh = grid_sizes[1], gw = grid_sizes[2];
  int sl = gf * gh * gw;
  int hw = gh * gw;
  int fi = row / hw, rem = row - fi * hw;
  int hi = rem / gw, wi = rem - hi * gw;
  bool dorope = row < sl;
#pragma unroll
  for (int i = 0; i < 3; ++i) {
    int p = t + i * 256;
    int j = p & 63;
    float a = xr[i] * rs * g[2 * p];
    float b = xi[i] * rs * g[2 * p + 1];
    if (dorope) {
      int pos = (j < 22) ? fi : ((j < 43) ? hi : wi);
      float cs = fcos[pos * 64 + j], sn = fsin[pos * 64 + j];
      float oa = a * cs - b * sn;
      float ob = a * sn + b * cs;
      a = oa; b = ob;
    }
    a *= osc; b *= osc;
    unsigned int packed = (unsigned int)f2bf(a) | ((unsigned int)f2bf(b) << 16);
    *(unsigned int*)&buf[(size_t)row * D_ + 2 * p] = packed;
  }
}

// ---------------- MFMA flash attention v4: LDS-shared K/V, 4 waves x 64q ----
// Block: 256 threads = 4 waves, each wave 64 q rows -> 256 q/block.
// Grid: 192 blocks (16 q-tiles x 12 heads), XCD-swizzled so each XCD streams
// <=2 heads (4 MB K/V -> L2-resident). K/V staged per 32-key step into
// double-buffered LDS via global_load_lds; the key permutation and
// fragment-major layouts are baked into the per-lane staging SOURCE map
// (dest must be lane-contiguous). No running max (scale folded into Q, exp2).
__global__ __launch_bounds__(256, 1) void attn4(const unsigned short* __restrict__ Qb,
                                                const unsigned short* __restrict__ Kb,
                                                const unsigned short* __restrict__ Vt,
                                                unsigned short* __restrict__ Ob,
                                                const int* __restrict__ seq_lens) {
  __shared__ unsigned short Ks[2][4096];  // 8 KB per buffer
  __shared__ unsigned short Vs[2][4096];
  int t = threadIdx.x, lane = t & 63, w = t >> 6;
  int id = blockIdx.x;
  int u = (id & 7) * 24 + (id >> 3);   // XCD swizzle (round-robin id->XCD)
  int h = u >> 4, qb = u & 15;
  int q0 = qb * 256 + w * 64;
  int seqlen = seq_lens[0];
  int fl = lane & 15, fg = lane >> 4;

  // Q B-fragments (pre-scaled): B[n=q][k=d]
  bf16x8 qf[4][4];
#pragma unroll
  for (int nj = 0; nj < 4; ++nj)
#pragma unroll
    for (int kd = 0; kd < 4; ++kd)
      qf[nj][kd] = *(const bf16x8*)&Qb[((size_t)(q0 + nj * 16 + fl) * NH + h) * HD + kd * 32 + fg * 8];

  // staging source pointers, chunk c = t and c = t+256 for K and V
  // K LDS layout: chunk = (kd*4+fg)*32 + mi*16 + fl (fragment-major, permuted keys)
  // V LDS layout: chunk = d*4 + kg  (d 0..127, kg = key-group of 8)
  const unsigned short* kp[2];
  const unsigned short* vp[2];
#pragma unroll
  for (int i = 0; i < 2; ++i) {
    int c = t + i * 256;
    int dgroup = c >> 5, permrow = c & 31;
    int kd = dgroup >> 2, fgc = dgroup & 3, mi = permrow >> 4, flc = permrow & 15;
    int key = (((flc & 12) << 1) | (flc & 3)) + (mi << 2);
    kp[i] = Kb + ((size_t)key * NH + h) * HD + kd * 32 + fgc * 8;
    int vd = c >> 2, vkg = c & 3;
    vp[i] = Vt + ((size_t)(h * HD + vd)) * 32 + vkg * 8;
  }
  const int STEP = 32 * NH * HD;  // == D_*32: advance for both K rows and V tiles

  auto stage = [&](int b) {
#pragma unroll
    for (int i = 0; i < 2; ++i) {
      __builtin_amdgcn_global_load_lds(
          (const __attribute__((address_space(1))) void*)kp[i],
          (__attribute__((address_space(3))) void*)&Ks[b][(i * 256 + w * 64) * 8],
          16, 0, 0);
      __builtin_amdgcn_global_load_lds(
          (const __attribute__((address_space(1))) void*)vp[i],
          (__attribute__((address_space(3))) void*)&Vs[b][(i * 256 + w * 64) * 8],
          16, 0, 0);
      kp[i] += STEP; vp[i] += STEP;
    }
  };

  floatx4 o[4][8];
  floatx4 zero = {0.f, 0.f, 0.f, 0.f};
#pragma unroll
  for (int nj = 0; nj < 4; ++nj)
#pragma unroll
    for (int nt = 0; nt < 8; ++nt) o[nj][nt] = zero;
  float lr[4] = {0.f, 0.f, 0.f, 0.f};

  stage(0);
  for (int kt = 0; kt < L_; kt += 32) {
    int cur = (kt >> 5) & 1;
    __syncthreads();                       // staged data for cur now visible
    if (kt + 32 < L_) stage(cur ^ 1);      // prefetch next (in flight during compute)

    // S^T = K.Q^T : rows = permuted keys, cols = q
    floatx4 s[2][4];
#pragma unroll
    for (int mi = 0; mi < 2; ++mi)
#pragma unroll
      for (int nj = 0; nj < 4; ++nj) s[mi][nj] = zero;
#pragma unroll
    for (int kd = 0; kd < 4; ++kd)
#pragma unroll
      for (int mi = 0; mi < 2; ++mi) {
        bf16x8 kf = *(const bf16x8*)&Ks[cur][(((kd << 2) | fg) * 32 + (mi << 4) + fl) * 8];
#pragma unroll
        for (int nj = 0; nj < 4; ++nj)
          s[mi][nj] = __builtin_amdgcn_mfma_f32_16x16x32_bf16(kf, qf[nj][kd], s[mi][nj], 0, 0, 0);
      }

    // softmax (no running max; exp2; scale pre-folded into Q)
    bf16x8 pb[4];
    bool full = (kt + 32 <= seqlen);
#pragma unroll
    for (int nj = 0; nj < 4; ++nj) {
      float p[8];
      if (full) {
#pragma unroll
        for (int mi = 0; mi < 2; ++mi)
#pragma unroll
          for (int r = 0; r < 4; ++r) p[mi * 4 + r] = EXP2F(s[mi][nj][r]);
      } else {
#pragma unroll
        for (int mi = 0; mi < 2; ++mi)
#pragma unroll
          for (int r = 0; r < 4; ++r) {
            int key = kt + fg * 8 + mi * 4 + r;
            p[mi * 4 + r] = (key < seqlen) ? EXP2F(s[mi][nj][r]) : 0.f;
          }
      }
      float sum = ((p[0] + p[1]) + (p[2] + p[3])) + ((p[4] + p[5]) + (p[6] + p[7]));
      sum += __shfl_xor(sum, 16);
      sum += __shfl_xor(sum, 32);
      lr[nj] += sum;
      union { unsigned int u[4]; bf16x8 v; } pk;
#pragma unroll
      for (int jj = 0; jj < 4; ++jj) {
        unsigned int a = __builtin_bit_cast(unsigned int, p[2 * jj]) + 0x8000u;
        unsigned int b = __builtin_bit_cast(unsigned int, p[2 * jj + 1]) + 0x8000u;
        pk.u[jj] = (a >> 16) | (b & 0xffff0000u);
      }
      pb[nj] = pk.v;
    }

    // PV: A = pb (registers), B = V d-rows from LDS
#pragma unroll
    for (int nt = 0; nt < 8; ++nt) {
      bf16x8 vf = *(const bf16x8*)&Vs[cur][((((nt << 4) + fl) << 2) + fg) * 8];
#pragma unroll
      for (int nj = 0; nj < 4; ++nj)
        o[nj][nt] = __builtin_amdgcn_mfma_f32_16x16x32_bf16(pb[nj], vf, o[nj][nt], 0, 0, 0);
    }
  }

  // epilogue: O /= l ; row q = q0+nj*16+fg*4+r, col d = nt*16+fl
#pragma unroll
  for (int nj = 0; nj < 4; ++nj) {
    float inv = 1.0f / lr[nj];
    float i0 = __shfl(inv, fg * 4 + 0);
    float i1 = __shfl(inv, fg * 4 + 1);
    float i2 = __shfl(inv, fg * 4 + 2);
    float i3 = __shfl(inv, fg * 4 + 3);
    int rowb = q0 + nj * 16 + fg * 4;
#pragma unroll
    for (int nt = 0; nt < 8; ++nt) {
      int dcol = h * HD + nt * 16 + fl;
      Ob[(size_t)(rowb + 0) * D_ + dcol] = f2bf(o[nj][nt][0] * i0);
      Ob[(size_t)(rowb + 1) * D_ + dcol] = f2bf(o[nj][nt][1] * i1);
      Ob[(size_t)(rowb + 2) * D_ + dcol] = f2bf(o[nj][nt][2] * i2);
      Ob[(size_t)(rowb + 3) * D_ + dcol] = f2bf(o[nj][nt][3] * i3);
    }
  }
}

// ---------------- launch ----------------
extern "C" void kernel_launch(void* const* d_in, const int* in_sizes, int n_in,
                              void* d_out, int out_size, void* d_ws, size_t ws_size,
                              hipStream_t stream) {
  (void)in_sizes; (void)n_in; (void)out_size;
  const float* x    = (const float*)d_in[0];
  const int* seqln  = (const int*)d_in[1];
  const int* gsz    = (const int*)d_in[2];
  const float* fcos = (const float*)d_in[3];
  const float* fsin = (const float*)d_in[4];
  const float* Wq = (const float*)d_in[5];
  const float* bq = (const float*)d_in[6];
  const float* Wk = (const float*)d_in[7];
  const float* bk = (const float*)d_in[8];
  const float* Wv = (const float*)d_in[9];
  const float* bv = (const float*)d_in[10];
  const float* Wo = (const float*)d_in[11];
  const float* bo = (const float*)d_in[12];
  const float* gq = (const float*)d_in[13];
  const float* gk = (const float*)d_in[14];

  char* ws = (char*)d_ws;
  size_t LD2 = (size_t)L_ * D_ * 2;      // 12.58 MB
  size_t WD2 = (size_t)D_ * D_ * 2;      // 4.72 MB
  unsigned short* xb  = (unsigned short*)(ws);            // x bf16; later attn out
  unsigned short* qb  = (unsigned short*)(ws + LD2);
  unsigned short* kb  = (unsigned short*)(ws + 2 * LD2);
  unsigned short* vtb = (unsigned short*)(ws + 3 * LD2);  // V, K-tiled transposed
  unsigned short* wb0 = (unsigned short*)(ws + 4 * LD2);
  unsigned short* ab  = xb;

  int nx8 = L_ * D_ / 8, nw8 = D_ * D_ / 8;
  dim3 gg(D_ / 128, L_ / 128);

  cvt_f32_bf16<<<(nx8 + 255) / 256, 256, 0, stream>>>(x, xb, nx8);

  if (ws_size >= 4 * LD2 + 3 * WD2) {
    unsigned short* wb1 = (unsigned short*)(ws + 4 * LD2 + WD2);
    unsigned short* wb2 = (unsigned short*)(ws + 4 * LD2 + 2 * WD2);
    cvt_f32_bf16<<<(nw8 + 255) / 256, 256, 0, stream>>>(Wq, wb0, nw8);
    cvt_f32_bf16<<<(nw8 + 255) / 256, 256, 0, stream>>>(Wk, wb1, nw8);
    cvt_f32_bf16<<<(nw8 + 255) / 256, 256, 0, stream>>>(Wv, wb2, nw8);
    gemm_qkv<<<dim3(3 * D_ / 128, L_ / 128), 256, 0, stream>>>(
        xb, wb0, wb1, wb2, bq, bk, bv, qb, kb, vtb);
  } else {
    cvt_f32_bf16<<<(nw8 + 255) / 256, 256, 0, stream>>>(Wq, wb0, nw8);
    gemm_bt<1><<<gg, 256, 0, stream>>>(xb, wb0, bq, qb, L_, D_, D_);
    cvt_f32_bf16<<<(nw8 + 255) / 256, 256, 0, stream>>>(Wk, wb0, nw8);
    gemm_bt<1><<<gg, 256, 0, stream>>>(xb, wb0, bk, kb, L_, D_, D_);
    cvt_f32_bf16<<<(nw8 + 255) / 256, 256, 0, stream>>>(Wv, wb0, nw8);
    gemm_bt<2><<<gg, 256, 0, stream>>>(xb, wb0, bv, vtb, L_, D_, D_);
  }

  rmsrope<<<dim3(L_, 2), 256, 0, stream>>>(qb, kb, gq, gk, fcos, fsin, gsz);

  attn4<<<dim3(192), 256, 0, stream>>>(qb, kb, vtb, ab, seqln);

  cvt_f32_bf16<<<(nw8 + 255) / 256, 256, 0, stream>>>(Wo, wb0, nw8);
  gemm_bt<0><<<gg, 256, 0, stream>>>(ab, wb0, bo, d_out, L_, D_, D_);
}

// Round 5
// 465.631 us; speedup vs baseline: 5.9018x; 1.1210x over previous
//
#include <hip/hip_runtime.h>

#define L_ 4096
#define D_ 1536
#define NH 12
#define HD 128

typedef __attribute__((ext_vector_type(8))) __bf16 bf16x8;
typedef __attribute__((ext_vector_type(8))) unsigned short ushort8v;
typedef __attribute__((ext_vector_type(4))) float floatx4;

#if __has_builtin(__builtin_amdgcn_exp2f)
#define EXP2F(x) __builtin_amdgcn_exp2f(x)
#else
#define EXP2F(x) exp2f(x)
#endif

__device__ __forceinline__ unsigned short f2bf(float f) {
  union { float f; unsigned int u; } v; v.f = f;
  unsigned int u = v.u;
  return (unsigned short)((u + 0x7fffu + ((u >> 16) & 1u)) >> 16);
}
__device__ __forceinline__ float bf2f(unsigned short h) {
  union { unsigned int u; float f; } v; v.u = ((unsigned int)h) << 16;
  return v.f;
}

// ---------------- fp32 -> bf16 conversion (8 elems/thread) ----------------
__global__ __launch_bounds__(256) void cvt_f32_bf16(const float* __restrict__ in,
                                                    unsigned short* __restrict__ out,
                                                    int n8) {
  int i = blockIdx.x * 256 + threadIdx.x;
  if (i >= n8) return;
  const float4* p = (const float4*)(in + (size_t)i * 8);
  float4 a = p[0], b = p[1];
  ushort8v o;
  o[0] = f2bf(a.x); o[1] = f2bf(a.y); o[2] = f2bf(a.z); o[3] = f2bf(a.w);
  o[4] = f2bf(b.x); o[5] = f2bf(b.y); o[6] = f2bf(b.z); o[7] = f2bf(b.w);
  *(ushort8v*)(out + (size_t)i * 8) = o;
}

// ---------------- GEMM core (m97 structure), shared by both GEMM kernels ----
template <int MODE>
__device__ __forceinline__ void gemm_core(const unsigned short* __restrict__ A,
                                          const unsigned short* __restrict__ Bw,
                                          const float* __restrict__ bias,
                                          void* __restrict__ Cout,
                                          int M, int Nn, int K,
                                          int m0, int n0,
                                          unsigned short* As, unsigned short* Bs) {
  int t = threadIdx.x;
  int lane = t & 63, wv = t >> 6;
  int wm = (wv & 1) * 64, wn = (wv >> 1) * 64;
  floatx4 zero = {0.f, 0.f, 0.f, 0.f};
  floatx4 acc[4][4];
#pragma unroll
  for (int i = 0; i < 4; ++i)
#pragma unroll
    for (int j = 0; j < 4; ++j) acc[i][j] = zero;
  int fm = lane & 15, fk = (lane >> 4) * 8;

  for (int kt = 0; kt < K; kt += 32) {
    __syncthreads();
#pragma unroll
    for (int it = 0; it < 2; ++it) {
      int c = it * 256 + t;
      int row = c >> 2, col = (c & 3) * 8;
      const unsigned short* ga = A + (size_t)(m0 + row) * K + kt + col;
      const unsigned short* gb = Bw + (size_t)(n0 + row) * K + kt + col;
      __builtin_amdgcn_global_load_lds(
          (const __attribute__((address_space(1))) void*)ga,
          (__attribute__((address_space(3))) void*)((char*)As + (it * 256 + wv * 64) * 16),
          16, 0, 0);
      __builtin_amdgcn_global_load_lds(
          (const __attribute__((address_space(1))) void*)gb,
          (__attribute__((address_space(3))) void*)((char*)Bs + (it * 256 + wv * 64) * 16),
          16, 0, 0);
    }
    __syncthreads();
    bf16x8 af[4], bfr[4];
#pragma unroll
    for (int i = 0; i < 4; ++i) {
      af[i]  = *(const bf16x8*)&As[(wm + 16 * i + fm) * 32 + fk];
      bfr[i] = *(const bf16x8*)&Bs[(wn + 16 * i + fm) * 32 + fk];
    }
#pragma unroll
    for (int i = 0; i < 4; ++i)
#pragma unroll
      for (int j = 0; j < 4; ++j)
        acc[i][j] = __builtin_amdgcn_mfma_f32_16x16x32_bf16(af[i], bfr[j], acc[i][j], 0, 0, 0);
  }

  int fr = (lane >> 4) * 4;
#pragma unroll
  for (int j = 0; j < 4; ++j) {
    int col = n0 + wn + 16 * j + fm;
    float bz = bias[col];
#pragma unroll
    for (int i = 0; i < 4; ++i) {
      int row0 = m0 + wm + 16 * i + fr;
      if (MODE == 2) {
        ushort4 pk = make_ushort4(f2bf(acc[i][j][0] + bz), f2bf(acc[i][j][1] + bz),
                                  f2bf(acc[i][j][2] + bz), f2bf(acc[i][j][3] + bz));
        size_t off = (size_t)(row0 >> 5) * Nn * 32 + (size_t)col * 32 + (row0 & 31);
        *(ushort4*)&((unsigned short*)Cout)[off] = pk;
      } else {
#pragma unroll
        for (int r = 0; r < 4; ++r) {
          float val = acc[i][j][r] + bz;
          if (MODE == 1) ((unsigned short*)Cout)[(size_t)(row0 + r) * Nn + col] = f2bf(val);
          else           ((float*)Cout)[(size_t)(row0 + r) * Nn + col] = val;
        }
      }
    }
  }
}

template <int MODE>
__global__ __launch_bounds__(256) void gemm_bt(const unsigned short* __restrict__ A,
                                               const unsigned short* __restrict__ Bw,
                                               const float* __restrict__ bias,
                                               void* __restrict__ Cout,
                                               int M, int Nn, int K) {
  __shared__ unsigned short As[128 * 32];
  __shared__ unsigned short Bs[128 * 32];
  gemm_core<MODE>(A, Bw, bias, Cout, M, Nn, K, blockIdx.y * 128, blockIdx.x * 128, As, Bs);
}

// Fused QKV: one dispatch, 1152 blocks.
__global__ __launch_bounds__(256) void gemm_qkv(const unsigned short* __restrict__ xb,
                                                const unsigned short* __restrict__ wq,
                                                const unsigned short* __restrict__ wk,
                                                const unsigned short* __restrict__ wv,
                                                const float* __restrict__ bq,
                                                const float* __restrict__ bk,
                                                const float* __restrict__ bv,
                                                unsigned short* __restrict__ outq,
                                                unsigned short* __restrict__ outk,
                                                unsigned short* __restrict__ outv) {
  __shared__ unsigned short As[128 * 32];
  __shared__ unsigned short Bs[128 * 32];
  int which = blockIdx.x / (D_ / 128);
  int n0 = (blockIdx.x % (D_ / 128)) * 128;
  int m0 = blockIdx.y * 128;
  if (which == 0)
    gemm_core<1>(xb, wq, bq, outq, L_, D_, D_, m0, n0, As, Bs);
  else if (which == 1)
    gemm_core<1>(xb, wk, bk, outk, L_, D_, D_, m0, n0, As, Bs);
  else
    gemm_core<2>(xb, wv, bv, outv, L_, D_, D_, m0, n0, As, Bs);
}

// ---------------- fused RMSNorm (over D) + 3-axis RoPE, in-place bf16 -------
__global__ __launch_bounds__(256) void rmsrope(unsigned short* __restrict__ qb,
                                               unsigned short* __restrict__ kb,
                                               const float* __restrict__ gq,
                                               const float* __restrict__ gk,
                                               const float* __restrict__ fcos,
                                               const float* __restrict__ fsin,
                                               const int* __restrict__ grid_sizes) {
  int row = blockIdx.x;
  unsigned short* buf = (blockIdx.y == 0) ? qb : kb;
  const float* g = (blockIdx.y == 0) ? gq : gk;
  float osc = (blockIdx.y == 0) ? 0.1275174475f : 1.0f;  // log2(e)/sqrt(128)
  int t = threadIdx.x;
  float xr[3], xi[3];
#pragma unroll
  for (int i = 0; i < 3; ++i) {
    int p = t + i * 256;
    unsigned int raw = *(const unsigned int*)&buf[(size_t)row * D_ + 2 * p];
    xr[i] = bf2f((unsigned short)(raw & 0xffffu));
    xi[i] = bf2f((unsigned short)(raw >> 16));
  }
  float ss = 0.f;
#pragma unroll
  for (int i = 0; i < 3; ++i) ss += xr[i] * xr[i] + xi[i] * xi[i];
  for (int off = 32; off > 0; off >>= 1) ss += __shfl_down(ss, off);
  __shared__ float red[4];
  if ((t & 63) == 0) red[t >> 6] = ss;
  __syncthreads();
  float rs = rsqrtf((red[0] + red[1] + red[2] + red[3]) * (1.0f / D_) + 1e-6f);

  int gf = grid_sizes[0], gh = grid_sizes[1], gw = grid_sizes[2];
  int sl = gf * gh * gw;
  int hw = gh * gw;
  int fi = row / hw, rem = row - fi * hw;
  int hi = rem / gw, wi = rem - hi * gw;
  bool dorope = row < sl;
#pragma unroll
  for (int i = 0; i < 3; ++i) {
    int p = t + i * 256;
    int j = p & 63;
    float a = xr[i] * rs * g[2 * p];
    float b = xi[i] * rs * g[2 * p + 1];
    if (dorope) {
      int pos = (j < 22) ? fi : ((j < 43) ? hi : wi);
      float cs = fcos[pos * 64 + j], sn = fsin[pos * 64 + j];
      float oa = a * cs - b * sn;
      float ob = a * sn + b * cs;
      a = oa; b = ob;
    }
    a *= osc; b *= osc;
    unsigned int packed = (unsigned int)f2bf(a) | ((unsigned int)f2bf(b) << 16);
    *(unsigned int*)&buf[(size_t)row * D_ + 2 * p] = packed;
  }
}

// ---------------- MFMA flash attention v5: 4 waves x 32q, grid 384 ----------
// Block: 256 threads = 4 waves, each wave 32 q rows -> 128 q/block.
// Grid: 384 blocks (32 q-tiles x 12 heads) -> ~6 waves/CU so MFMA and VALU
// of different waves co-schedule per SIMD (the R4 fix was traffic; this is
// the parallelism fix). XCD-swizzled: each XCD streams 1.5 heads (3 MB K/V).
__global__ __launch_bounds__(256, 2) void attn5(const unsigned short* __restrict__ Qb,
                                                const unsigned short* __restrict__ Kb,
                                                const unsigned short* __restrict__ Vt,
                                                unsigned short* __restrict__ Ob,
                                                const int* __restrict__ seq_lens) {
  __shared__ unsigned short Ks[2][4096];  // 8 KB per buffer
  __shared__ unsigned short Vs[2][4096];
  int t = threadIdx.x, lane = t & 63, w = t >> 6;
  int id = blockIdx.x;
  int u = (id & 7) * 48 + (id >> 3);   // XCD swizzle: 48 consecutive u per XCD
  int h = u >> 5, qt = u & 31;
  int q0 = qt * 128 + w * 32;
  int seqlen = seq_lens[0];
  int fl = lane & 15, fg = lane >> 4;

  // Q B-fragments (pre-scaled): B[n=q][k=d]
  bf16x8 qf[2][4];
#pragma unroll
  for (int nj = 0; nj < 2; ++nj)
#pragma unroll
    for (int kd = 0; kd < 4; ++kd)
      qf[nj][kd] = *(const bf16x8*)&Qb[((size_t)(q0 + nj * 16 + fl) * NH + h) * HD + kd * 32 + fg * 8];

  // staging source pointers (key permutation + fragment-major layouts baked in)
  const unsigned short* kp[2];
  const unsigned short* vp[2];
#pragma unroll
  for (int i = 0; i < 2; ++i) {
    int c = t + i * 256;
    int dgroup = c >> 5, permrow = c & 31;
    int kd = dgroup >> 2, fgc = dgroup & 3, mi = permrow >> 4, flc = permrow & 15;
    int key = (((flc & 12) << 1) | (flc & 3)) + (mi << 2);
    kp[i] = Kb + ((size_t)key * NH + h) * HD + kd * 32 + fgc * 8;
    int vd = c >> 2, vkg = c & 3;
    vp[i] = Vt + ((size_t)(h * HD + vd)) * 32 + vkg * 8;
  }
  const int STEP = 32 * NH * HD;

  auto stage = [&](int b) {
#pragma unroll
    for (int i = 0; i < 2; ++i) {
      __builtin_amdgcn_global_load_lds(
          (const __attribute__((address_space(1))) void*)kp[i],
          (__attribute__((address_space(3))) void*)&Ks[b][(i * 256 + w * 64) * 8],
          16, 0, 0);
      __builtin_amdgcn_global_load_lds(
          (const __attribute__((address_space(1))) void*)vp[i],
          (__attribute__((address_space(3))) void*)&Vs[b][(i * 256 + w * 64) * 8],
          16, 0, 0);
      kp[i] += STEP; vp[i] += STEP;
    }
  };

  floatx4 o[2][8];
  floatx4 zero = {0.f, 0.f, 0.f, 0.f};
#pragma unroll
  for (int nj = 0; nj < 2; ++nj)
#pragma unroll
    for (int nt = 0; nt < 8; ++nt) o[nj][nt] = zero;
  float lr[2] = {0.f, 0.f};

  stage(0);
  for (int kt = 0; kt < L_; kt += 32) {
    int cur = (kt >> 5) & 1;
    __syncthreads();
    if (kt + 32 < L_) stage(cur ^ 1);

    // S^T = K.Q^T
    floatx4 s[2][2];
    s[0][0] = zero; s[0][1] = zero; s[1][0] = zero; s[1][1] = zero;
#pragma unroll
    for (int kd = 0; kd < 4; ++kd)
#pragma unroll
      for (int mi = 0; mi < 2; ++mi) {
        bf16x8 kf = *(const bf16x8*)&Ks[cur][(((kd << 2) | fg) * 32 + (mi << 4) + fl) * 8];
#pragma unroll
        for (int nj = 0; nj < 2; ++nj)
          s[mi][nj] = __builtin_amdgcn_mfma_f32_16x16x32_bf16(kf, qf[nj][kd], s[mi][nj], 0, 0, 0);
      }

    // softmax (no running max; exp2; scale pre-folded into Q)
    bf16x8 pb[2];
    bool full = (kt + 32 <= seqlen);
#pragma unroll
    for (int nj = 0; nj < 2; ++nj) {
      float p[8];
      if (full) {
#pragma unroll
        for (int mi = 0; mi < 2; ++mi)
#pragma unroll
          for (int r = 0; r < 4; ++r) p[mi * 4 + r] = EXP2F(s[mi][nj][r]);
      } else {
#pragma unroll
        for (int mi = 0; mi < 2; ++mi)
#pragma unroll
          for (int r = 0; r < 4; ++r) {
            int key = kt + fg * 8 + mi * 4 + r;
            p[mi * 4 + r] = (key < seqlen) ? EXP2F(s[mi][nj][r]) : 0.f;
          }
      }
      float sum = ((p[0] + p[1]) + (p[2] + p[3])) + ((p[4] + p[5]) + (p[6] + p[7]));
      sum += __shfl_xor(sum, 16);
      sum += __shfl_xor(sum, 32);
      lr[nj] += sum;
      union { unsigned int u[4]; bf16x8 v; } pk;
#pragma unroll
      for (int jj = 0; jj < 4; ++jj) {
        unsigned int a = __builtin_bit_cast(unsigned int, p[2 * jj]) + 0x8000u;
        unsigned int b = __builtin_bit_cast(unsigned int, p[2 * jj + 1]) + 0x8000u;
        pk.u[jj] = (a >> 16) | (b & 0xffff0000u);
      }
      pb[nj] = pk.v;
    }

    // PV: A = pb (registers), B = V d-rows from LDS
#pragma unroll
    for (int nt = 0; nt < 8; ++nt) {
      bf16x8 vf = *(const bf16x8*)&Vs[cur][((((nt << 4) + fl) << 2) + fg) * 8];
#pragma unroll
      for (int nj = 0; nj < 2; ++nj)
        o[nj][nt] = __builtin_amdgcn_mfma_f32_16x16x32_bf16(pb[nj], vf, o[nj][nt], 0, 0, 0);
    }
  }

  // epilogue
#pragma unroll
  for (int nj = 0; nj < 2; ++nj) {
    float inv = 1.0f / lr[nj];
    float i0 = __shfl(inv, fg * 4 + 0);
    float i1 = __shfl(inv, fg * 4 + 1);
    float i2 = __shfl(inv, fg * 4 + 2);
    float i3 = __shfl(inv, fg * 4 + 3);
    int rowb = q0 + nj * 16 + fg * 4;
#pragma unroll
    for (int nt = 0; nt < 8; ++nt) {
      int dcol = h * HD + nt * 16 + fl;
      Ob[(size_t)(rowb + 0) * D_ + dcol] = f2bf(o[nj][nt][0] * i0);
      Ob[(size_t)(rowb + 1) * D_ + dcol] = f2bf(o[nj][nt][1] * i1);
      Ob[(size_t)(rowb + 2) * D_ + dcol] = f2bf(o[nj][nt][2] * i2);
      Ob[(size_t)(rowb + 3) * D_ + dcol] = f2bf(o[nj][nt][3] * i3);
    }
  }
}

// ---------------- launch ----------------
extern "C" void kernel_launch(void* const* d_in, const int* in_sizes, int n_in,
                              void* d_out, int out_size, void* d_ws, size_t ws_size,
                              hipStream_t stream) {
  (void)in_sizes; (void)n_in; (void)out_size;
  const float* x    = (const float*)d_in[0];
  const int* seqln  = (const int*)d_in[1];
  const int* gsz    = (const int*)d_in[2];
  const float* fcos = (const float*)d_in[3];
  const float* fsin = (const float*)d_in[4];
  const float* Wq = (const float*)d_in[5];
  const float* bq = (const float*)d_in[6];
  const float* Wk = (const float*)d_in[7];
  const float* bk = (const float*)d_in[8];
  const float* Wv = (const float*)d_in[9];
  const float* bv = (const float*)d_in[10];
  const float* Wo = (const float*)d_in[11];
  const float* bo = (const float*)d_in[12];
  const float* gq = (const float*)d_in[13];
  const float* gk = (const float*)d_in[14];

  char* ws = (char*)d_ws;
  size_t LD2 = (size_t)L_ * D_ * 2;      // 12.58 MB
  size_t WD2 = (size_t)D_ * D_ * 2;      // 4.72 MB
  unsigned short* xb  = (unsigned short*)(ws);            // x bf16; later attn out
  unsigned short* qb  = (unsigned short*)(ws + LD2);
  unsigned short* kb  = (unsigned short*)(ws + 2 * LD2);
  unsigned short* vtb = (unsigned short*)(ws + 3 * LD2);  // V, K-tiled transposed
  unsigned short* wb0 = (unsigned short*)(ws + 4 * LD2);
  unsigned short* ab  = xb;

  int nx8 = L_ * D_ / 8, nw8 = D_ * D_ / 8;
  dim3 gg(D_ / 128, L_ / 128);

  cvt_f32_bf16<<<(nx8 + 255) / 256, 256, 0, stream>>>(x, xb, nx8);

  if (ws_size >= 4 * LD2 + 3 * WD2) {
    unsigned short* wb1 = (unsigned short*)(ws + 4 * LD2 + WD2);
    unsigned short* wb2 = (unsigned short*)(ws + 4 * LD2 + 2 * WD2);
    cvt_f32_bf16<<<(nw8 + 255) / 256, 256, 0, stream>>>(Wq, wb0, nw8);
    cvt_f32_bf16<<<(nw8 + 255) / 256, 256, 0, stream>>>(Wk, wb1, nw8);
    cvt_f32_bf16<<<(nw8 + 255) / 256, 256, 0, stream>>>(Wv, wb2, nw8);
    gemm_qkv<<<dim3(3 * D_ / 128, L_ / 128), 256, 0, stream>>>(
        xb, wb0, wb1, wb2, bq, bk, bv, qb, kb, vtb);
  } else {
    cvt_f32_bf16<<<(nw8 + 255) / 256, 256, 0, stream>>>(Wq, wb0, nw8);
    gemm_bt<1><<<gg, 256, 0, stream>>>(xb, wb0, bq, qb, L_, D_, D_);
    cvt_f32_bf16<<<(nw8 + 255) / 256, 256, 0, stream>>>(Wk, wb0, nw8);
    gemm_bt<1><<<gg, 256, 0, stream>>>(xb, wb0, bk, kb, L_, D_, D_);
    cvt_f32_bf16<<<(nw8 + 255) / 256, 256, 0, stream>>>(Wv, wb0, nw8);
    gemm_bt<2><<<gg, 256, 0, stream>>>(xb, wb0, bv, vtb, L_, D_, D_);
  }

  rmsrope<<<dim3(L_, 2), 256, 0, stream>>>(qb, kb, gq, gk, fcos, fsin, gsz);

  attn5<<<dim3(384), 256, 0, stream>>>(qb, kb, vtb, ab, seqln);

  cvt_f32_bf16<<<(nw8 + 255) / 256, 256, 0, stream>>>(Wo, wb0, nw8);
  gemm_bt<0><<<gg, 256, 0, stream>>>(ab, wb0, bo, d_out, L_, D_, D_);
}